// Round 4
// baseline (589.548 us; speedup 1.0000x reference)
//
#include <hip/hip_runtime.h>
#include <math.h>

// B=16384, D=4096 (+3 tail features), H=128, E=64, K=8
#define DGL 4096
#define HGL 128
#define EGL 64
#define DELTA 5e-4f    // top8/9 gap threshold for fp32 recompute (split err sigma ~1.5e-5)

typedef short  short8 __attribute__((ext_vector_type(8)));
typedef float  f32x4  __attribute__((ext_vector_type(4)));

__device__ inline unsigned short bf16_rne(float x) {
    unsigned u = __float_as_uint(x);
    u += 0x7FFFu + ((u >> 16) & 1u);
    return (unsigned short)(u >> 16);
}
// truncation-hi + RNE-lo split: hi+lo represents x to ~2^-17 rel
__device__ inline void split2(float x, short& hi, short& lo) {
    unsigned u = __float_as_uint(x);
    hi = (short)(u >> 16);
    float hif = __uint_as_float(u & 0xFFFF0000u);
    lo = (short)bf16_rne(x - hif);
}
__device__ inline void split8(const float* f, short8& hi, short8& lo) {
#pragma unroll
    for (int j = 0; j < 8; ++j) { short h, l2; split2(f[j], h, l2); hi[j] = h; lo[j] = l2; }
}

// ---- pack W1[0:4096] into bf16 hi/lo MFMA B-fragments (layout verified round 2/3) ----
// wsB1[kci*8192 + ((nt*2+h)*64 + lane)*8 + j]; lane l holds B[k=kci*32+(l>>4)*8+j][n=nt*16+(l&15)]
__global__ void pack_w1(const float* __restrict__ W1, unsigned short* __restrict__ wsB1) {
    const int b = blockIdx.x;              // 1024 = 128 kci * 8 nt
    const int kci = b >> 3, nt = b & 7;
    const int l = threadIdx.x, quad = l >> 4, l15 = l & 15;
    short8 vh, vl;
#pragma unroll
    for (int j = 0; j < 8; ++j) {
        const int k = kci * 32 + quad * 8 + j;
        short h, lo; split2(W1[(size_t)k * HGL + nt * 16 + l15], h, lo);
        vh[j] = h; vl[j] = lo;
    }
    *(short8*)(wsB1 + (size_t)kci * 8192 + ((nt * 2 + 0) * 64 + l) * 8) = vh;
    *(short8*)(wsB1 + (size_t)kci * 8192 + ((nt * 2 + 1) * 64 + l) * 8) = vl;
}

// ---- pack W2 (128x64) frags; also zero the refine-list counter ----
__global__ void pack_w2(const float* __restrict__ W2, unsigned short* __restrict__ wsB2,
                        int* __restrict__ gcount) {
    if (blockIdx.x == 0 && threadIdx.x == 0) *gcount = 0;
    const int b = blockIdx.x;              // 16 = 4 kc2 * 4 nt
    const int kc2 = b >> 2, nt = b & 3;
    const int l = threadIdx.x, quad = l >> 4, l15 = l & 15;
    short8 vh, vl;
#pragma unroll
    for (int j = 0; j < 8; ++j) {
        const int k = kc2 * 32 + quad * 8 + j;
        short h, lo; split2(W2[k * EGL + nt * 16 + l15], h, lo);
        vh[j] = h; vl[j] = lo;
    }
    *(short8*)(wsB2 + ((kc2 * 4 + nt) * 2 + 0) * 512 + l * 8) = vh;
    *(short8*)(wsB2 + ((kc2 * 4 + nt) * 2 + 1) * 512 + l * 8) = vl;
}

// ---- main: 512 threads = 8 waves, 32 rows/block ----
// Occupancy model (rounds 0/2/3): unified VGPR+AGPR file, 512/lane, 64-reg granule;
// waves/SIMD = 512 / roundup64(VGPR+AGPR). Old acc[2][8]=64 AGPR + ~72 VGPR = 192
// -> 2 waves/SIMD (22% occ, latency-bound at ~245us).
// Fix: wave (kq=w&3, mh=w>>2) computes 16 rows x 128 cols over a 1024-wide K range:
// acc[8] = 32 AGPR, A-state halved -> total <= 128 -> 4 waves/SIMD.
__global__ __launch_bounds__(512, 2) void router_main(
    const float* __restrict__ r_pooled, const float* __restrict__ step_frac,
    const float* __restrict__ hn, const float* __restrict__ cf,
    const float* __restrict__ W1, const float* __restrict__ b1,
    const float* __restrict__ b2v,
    const unsigned short* __restrict__ wsB1, const unsigned short* __restrict__ wsB2,
    int* __restrict__ gcount, int* __restrict__ glist,
    float* __restrict__ out_w, float* __restrict__ out_l)
{
    __shared__ float hsum[32 * 132];   // reduced h, [row][col] stride 132
    __shared__ float ls[32 * 65];      // logits tile for topk
    __shared__ float wt[32 * 65];      // weights tile

    const int t = threadIdx.x;
    const int w = t >> 6, l = t & 63;
    const int quad = l >> 4, l15 = l & 15;
    const int row0 = blockIdx.x * 32;

    const int kq = w & 3, mh = w >> 2;
    // this wave: rows [row0+mh*16, +16), K-range [kq*1024, +1024)
    const float* aB = r_pooled + (size_t)(row0 + mh * 16 + l15) * DGL + kq * 1024 + quad * 8;

    f32x4 acc[8];
#pragma unroll
    for (int nt = 0; nt < 8; ++nt) acc[nt] = (f32x4){0.f, 0.f, 0.f, 0.f};

    float4 a0[2];
    a0[0] = *(const float4*)(aB);
    a0[1] = *(const float4*)(aB + 4);

    for (int kci = 0; kci < 32; ++kci) {
        // split current A slice into MFMA fragments (a0 dead afterwards)
        short8 ahi, alo;
        {
            float fa[8];
#pragma unroll
            for (int j = 0; j < 4; ++j) { fa[j] = a0[0][j]; fa[j + 4] = a0[1][j]; }
            split8(fa, ahi, alo);
        }
        // prefetch next A slice into the SAME registers (hidden under MFMAs)
        if (kci + 1 < 32) {
            a0[0] = *(const float4*)(aB + (kci + 1) * 32);
            a0[1] = *(const float4*)(aB + (kci + 1) * 32 + 4);
        }

        const unsigned short* bp = wsB1 + (size_t)(kq * 32 + kci) * 8192 + l * 8;
        // B pipeline: 2-deep (one nt-pair in flight)
        short8 bh = *(const short8*)(bp + 0 * 512);
        short8 bl = *(const short8*)(bp + 1 * 512);
#pragma unroll
        for (int nt = 0; nt < 8; ++nt) {
            short8 bhn, bln;
            if (nt < 7) {
                bhn = *(const short8*)(bp + (2 * nt + 2) * 512);
                bln = *(const short8*)(bp + (2 * nt + 3) * 512);
            }
            acc[nt] = __builtin_amdgcn_mfma_f32_16x16x32_bf16(ahi, bh, acc[nt], 0, 0, 0);
            acc[nt] = __builtin_amdgcn_mfma_f32_16x16x32_bf16(ahi, bl, acc[nt], 0, 0, 0);
            acc[nt] = __builtin_amdgcn_mfma_f32_16x16x32_bf16(alo, bh, acc[nt], 0, 0, 0);
            bh = bhn; bl = bln;
        }
    }

    // ---- reduce the 4 K-partials per row-half (both mh trees in parallel) ----
    // C layout: row = mh*16 + quad*4 + r, col = nt*16 + l15
    if (kq == 0) {
#pragma unroll
        for (int nt = 0; nt < 8; ++nt)
#pragma unroll
            for (int r = 0; r < 4; ++r)
                hsum[(mh * 16 + quad * 4 + r) * 132 + nt * 16 + l15] = acc[nt][r];
    }
    __syncthreads();
#pragma unroll
    for (int wv = 1; wv < 4; ++wv) {
        if (kq == wv) {
#pragma unroll
            for (int nt = 0; nt < 8; ++nt)
#pragma unroll
                for (int r = 0; r < 4; ++r)
                    hsum[(mh * 16 + quad * 4 + r) * 132 + nt * 16 + l15] += acc[nt][r];
        }
        __syncthreads();
    }

    // ---- epilogue: tail features + bias + silu, in place on hsum ----
    {
        const float sf = step_frac[0];
#pragma unroll
        for (int j = 0; j < 8; ++j) {
            const int idx = j * 512 + t;      // 0..4095
            const int r = idx >> 7, c = idx & 127;
            float x = hsum[r * 132 + c];
            x += sf * W1[(size_t)4096 * HGL + c]
               + hn[row0 + r] * W1[(size_t)4097 * HGL + c]
               + cf[row0 + r] * W1[(size_t)4098 * HGL + c] + b1[c];
            hsum[r * 132 + c] = x / (1.0f + expf(-x));
        }
    }
    __syncthreads();

    // ---- GEMM2 via MFMA: each of the 8 waves does one 16-row x 16-col quadrant ----
    const int mt2 = w >> 2, nt2 = w & 3;
    f32x4 acc2 = (f32x4){0.f, 0.f, 0.f, 0.f};
#pragma unroll
    for (int kc2 = 0; kc2 < 4; ++kc2) {
        const float4 va = *(const float4*)&hsum[(mt2 * 16 + l15) * 132 + kc2 * 32 + quad * 8];
        const float4 vb = *(const float4*)&hsum[(mt2 * 16 + l15) * 132 + kc2 * 32 + quad * 8 + 4];
        float fa[8];
#pragma unroll
        for (int j = 0; j < 4; ++j) { fa[j] = ((const float*)&va)[j]; fa[j + 4] = ((const float*)&vb)[j]; }
        short8 h2, lo2;
        split8(fa, h2, lo2);
        const short8 bh = *(const short8*)(wsB2 + ((kc2 * 4 + nt2) * 2 + 0) * 512 + l * 8);
        const short8 bl = *(const short8*)(wsB2 + ((kc2 * 4 + nt2) * 2 + 1) * 512 + l * 8);
        acc2 = __builtin_amdgcn_mfma_f32_16x16x32_bf16(h2,  bh, acc2, 0, 0, 0);
        acc2 = __builtin_amdgcn_mfma_f32_16x16x32_bf16(h2,  bl, acc2, 0, 0, 0);
        acc2 = __builtin_amdgcn_mfma_f32_16x16x32_bf16(lo2, bh, acc2, 0, 0, 0);
    }

    // ---- logits out + ls stage, zero wt ----
    {
        const int c = nt2 * 16 + l15;
        const float bv = b2v[c];
#pragma unroll
        for (int r = 0; r < 4; ++r) {
            const int lr = mt2 * 16 + quad * 4 + r;
            const float v = acc2[r] + bv;
            out_l[(size_t)(row0 + lr) * EGL + c] = v;
            ls[lr * 65 + c] = v;
        }
    }
    for (int i = t; i < 32 * 65; i += 512) wt[i] = 0.0f;
    __syncthreads();

    // ---- top-8 (+9th for gap), softmax, scatter, flag near-ties ----
    if (t < 32) {
        float vals[9]; int idxs[9];
#pragma unroll
        for (int i = 0; i < 9; ++i) { vals[i] = -INFINITY; idxs[i] = 0; }
        for (int e = 0; e < EGL; ++e) {
            const float v = ls[t * 65 + e];
            if (v > vals[8]) {
                int p = 8;
                while (p > 0 && v > vals[p - 1]) { vals[p] = vals[p - 1]; idxs[p] = idxs[p - 1]; --p; }
                vals[p] = v; idxs[p] = e;
            }
        }
        const float mx = vals[0];
        float wgt[8], ssum = 0.0f;
#pragma unroll
        for (int i = 0; i < 8; ++i) { wgt[i] = expf(vals[i] - mx); ssum += wgt[i]; }
        const float inv = 1.0f / ssum;
#pragma unroll
        for (int i = 0; i < 8; ++i) wt[t * 65 + idxs[i]] = wgt[i] * inv;
        if (vals[7] - vals[8] < DELTA) {
            int p = atomicAdd(gcount, 1);
            if (p < 16384) glist[p] = row0 + t;
        }
    }
    __syncthreads();

    for (int i = t; i < 32 * EGL; i += 512) {
        const int m = i >> 6, c = i & 63;
        out_w[(size_t)(row0 + m) * EGL + c] = wt[m * 65 + c];
    }
}

// ---- refine: fp32 recompute of listed rows ----
__global__ __launch_bounds__(512, 1) void refine_rows(
    const float* __restrict__ r_pooled, const float* __restrict__ step_frac,
    const float* __restrict__ hn, const float* __restrict__ cf,
    const float* __restrict__ W1, const float* __restrict__ b1,
    const float* __restrict__ W2, const float* __restrict__ b2,
    const int* __restrict__ gcount, const int* __restrict__ glist,
    float* __restrict__ out_w)
{
    __shared__ __align__(16) float als[DGL];
    __shared__ float part[4][128];
    __shared__ float hred[128];
    __shared__ float lb[64];
    __shared__ float wb[64];

    const int t = threadIdx.x;
    const int cnt = *gcount;
    const int c = t & 127, sl = t >> 7;

    for (int i = blockIdx.x; i < cnt; i += gridDim.x) {
        const int row = glist[i];
        __syncthreads();
        for (int j = t; j < DGL / 4; j += 512)
            *(float4*)&als[j * 4] = *(const float4*)&r_pooled[(size_t)row * DGL + j * 4];
        __syncthreads();

        float pr = 0.0f;
        const float* ap = als + sl * 1024;
        const float* wp = W1 + (size_t)(sl * 1024) * HGL + c;
#pragma unroll 8
        for (int k = 0; k < 1024; ++k) pr = fmaf(ap[k], wp[(size_t)k * HGL], pr);
        part[sl][c] = pr;
        __syncthreads();

        if (t < 128) {
            const float sf = step_frac[0];
            float x = part[0][t] + part[1][t] + part[2][t] + part[3][t];
            x += sf * W1[(size_t)4096 * HGL + t] + hn[row] * W1[(size_t)4097 * HGL + t]
               + cf[row] * W1[(size_t)4098 * HGL + t] + b1[t];
            hred[t] = x / (1.0f + expf(-x));
        }
        __syncthreads();
        if (t < 64) {
            float a = b2[t];
            for (int k = 0; k < HGL; ++k) a = fmaf(hred[k], W2[k * EGL + t], a);
            lb[t] = a; wb[t] = 0.0f;
        }
        __syncthreads();
        if (t == 0) {
            float vals[8]; int idxs[8];
#pragma unroll
            for (int q = 0; q < 8; ++q) { vals[q] = -INFINITY; idxs[q] = 0; }
            for (int e = 0; e < EGL; ++e) {
                const float v = lb[e];
                if (v > vals[7]) {
                    int p = 7;
                    while (p > 0 && v > vals[p - 1]) { vals[p] = vals[p - 1]; idxs[p] = idxs[p - 1]; --p; }
                    vals[p] = v; idxs[p] = e;
                }
            }
            const float mx = vals[0];
            float wgt[8], ssum = 0.0f;
#pragma unroll
            for (int q = 0; q < 8; ++q) { wgt[q] = expf(vals[q] - mx); ssum += wgt[q]; }
            const float inv = 1.0f / ssum;
#pragma unroll
            for (int q = 0; q < 8; ++q) wb[idxs[q]] = wgt[q] * inv;
        }
        __syncthreads();
        if (t < 64) out_w[(size_t)row * EGL + t] = wb[t];
    }
}

extern "C" void kernel_launch(void* const* d_in, const int* in_sizes, int n_in,
                              void* d_out, int out_size, void* d_ws, size_t ws_size,
                              hipStream_t stream) {
    const float* r_pooled    = (const float*)d_in[0];
    const float* step_frac   = (const float*)d_in[1];
    const float* hidden_norm = (const float*)d_in[2];
    const float* confidence  = (const float*)d_in[3];
    const float* W1          = (const float*)d_in[4];
    const float* b1          = (const float*)d_in[5];
    const float* W2          = (const float*)d_in[6];
    const float* b2          = (const float*)d_in[7];

    const int B = in_sizes[2];
    float* out_w = (float*)d_out;
    float* out_l = out_w + (size_t)B * EGL;

    unsigned short* wsB1 = (unsigned short*)d_ws;                    // 2 MB
    unsigned short* wsB2 = (unsigned short*)((char*)d_ws + 2097152); // 32 KB
    int* gcount = (int*)((char*)d_ws + 2129920);
    int* glist  = (int*)((char*)d_ws + 2129984);                     // 64 KB

    hipLaunchKernelGGL(pack_w1, dim3(1024), dim3(64), 0, stream, W1, wsB1);
    hipLaunchKernelGGL(pack_w2, dim3(16), dim3(64), 0, stream, W2, wsB2, gcount);
    hipLaunchKernelGGL(router_main, dim3(B / 32), dim3(512), 0, stream,
                       r_pooled, step_frac, hidden_norm, confidence,
                       W1, b1, b2, wsB1, wsB2, gcount, glist, out_w, out_l);
    hipLaunchKernelGGL(refine_rows, dim3(256), dim3(512), 0, stream,
                       r_pooled, step_frac, hidden_norm, confidence,
                       W1, b1, W2, b2, gcount, glist, out_w);
}

// Round 5
// 545.720 us; speedup vs baseline: 1.0803x; 1.0803x over previous
//
#include <hip/hip_runtime.h>
#include <math.h>

// B=16384, D=4096 (+3 tail features), H=128, E=64, K=8
#define DGL 4096
#define HGL 128
#define EGL 64
#define DELTA 5e-4f    // top8/9 gap threshold for fp32 recompute (split err sigma ~1.5e-5)

typedef short  short8 __attribute__((ext_vector_type(8)));
typedef float  f32x4  __attribute__((ext_vector_type(4)));

__device__ inline unsigned short bf16_rne(float x) {
    unsigned u = __float_as_uint(x);
    u += 0x7FFFu + ((u >> 16) & 1u);
    return (unsigned short)(u >> 16);
}
// truncation-hi + RNE-lo split: hi+lo represents x to ~2^-17 rel
__device__ inline void split2(float x, short& hi, short& lo) {
    unsigned u = __float_as_uint(x);
    hi = (short)(u >> 16);
    float hif = __uint_as_float(u & 0xFFFF0000u);
    lo = (short)bf16_rne(x - hif);
}
__device__ inline void split8(const float* f, short8& hi, short8& lo) {
#pragma unroll
    for (int j = 0; j < 8; ++j) { short h, l2; split2(f[j], h, l2); hi[j] = h; lo[j] = l2; }
}

__device__ inline void gload_lds16(const void* g, void* l) {
    __builtin_amdgcn_global_load_lds((const __attribute__((address_space(1))) void*)g,
                                     (__attribute__((address_space(3))) void*)l, 16, 0, 0);
}

// ---- pack W1[0:4096] into bf16 hi/lo MFMA B-fragments (layout verified round 2/3) ----
// wsB1[kci*8192 + ((nt*2+h)*64 + lane)*8 + j]; lane l holds B[k=kci*32+(l>>4)*8+j][n=nt*16+(l&15)]
__global__ void pack_w1(const float* __restrict__ W1, unsigned short* __restrict__ wsB1) {
    const int b = blockIdx.x;              // 1024 = 128 kci * 8 nt
    const int kci = b >> 3, nt = b & 7;
    const int l = threadIdx.x, quad = l >> 4, l15 = l & 15;
    short8 vh, vl;
#pragma unroll
    for (int j = 0; j < 8; ++j) {
        const int k = kci * 32 + quad * 8 + j;
        short h, lo; split2(W1[(size_t)k * HGL + nt * 16 + l15], h, lo);
        vh[j] = h; vl[j] = lo;
    }
    *(short8*)(wsB1 + (size_t)kci * 8192 + ((nt * 2 + 0) * 64 + l) * 8) = vh;
    *(short8*)(wsB1 + (size_t)kci * 8192 + ((nt * 2 + 1) * 64 + l) * 8) = vl;
}

// ---- pack W2 (128x64) frags; also zero the refine-list counter ----
__global__ void pack_w2(const float* __restrict__ W2, unsigned short* __restrict__ wsB2,
                        int* __restrict__ gcount) {
    if (blockIdx.x == 0 && threadIdx.x == 0) *gcount = 0;
    const int b = blockIdx.x;              // 16 = 4 kc2 * 4 nt
    const int kc2 = b >> 2, nt = b & 3;
    const int l = threadIdx.x, quad = l >> 4, l15 = l & 15;
    short8 vh, vl;
#pragma unroll
    for (int j = 0; j < 8; ++j) {
        const int k = kc2 * 32 + quad * 8 + j;
        short h, lo; split2(W2[k * EGL + nt * 16 + l15], h, lo);
        vh[j] = h; vl[j] = lo;
    }
    *(short8*)(wsB2 + ((kc2 * 4 + nt) * 2 + 0) * 512 + l * 8) = vh;
    *(short8*)(wsB2 + ((kc2 * 4 + nt) * 2 + 1) * 512 + l * 8) = vl;
}

// ---- main: 64 rows/block, grid B/64 = 256 = 1 block/CU, 512 threads = 8 waves ----
// Theory (rounds 0/4): per-CU L1/TCP traffic for B-fragments is the wall (~8 MB/CU,
// invariant to occupancy). Fix: (a) 64-row blocks -> each CU reads wsB1 (2 MB) once;
// (b) B staged via global_load_lds into 2x64KB LDS dbuf, shared by the kq-pair waves;
// (c) one RAW s_barrier per kci: A-prefetch issued AFTER stage loads, so the
//     compiler's a0-wait transitively retires the (in-order-earlier) stage DMA.
// Wave w: kq=w&3 (K-range kq*1024..+1024), mh=w>>2 (rows mh*32..+32, 2 m-tiles).
__global__ __launch_bounds__(512, 1) void router_main(
    const float* __restrict__ r_pooled, const float* __restrict__ step_frac,
    const float* __restrict__ hn, const float* __restrict__ cf,
    const float* __restrict__ W1, const float* __restrict__ b1,
    const float* __restrict__ b2v,
    const unsigned short* __restrict__ wsB1, const unsigned short* __restrict__ wsB2,
    int* __restrict__ gcount, int* __restrict__ glist,
    float* __restrict__ out_w, float* __restrict__ out_l)
{
    // [s][kq][16KB] staging = 128 KB; aliased by hsum/ls/wt after the K-loop
    __shared__ __align__(16) char smem[131072];

    const int t = threadIdx.x;
    const int w = t >> 6, l = t & 63;
    const int quad = l >> 4, l15 = l & 15;
    const int row0 = blockIdx.x * 64;
    const int kq = w & 3, mh = w >> 2;

    const float* aB0 = r_pooled + (size_t)(row0 + mh * 32 + l15) * DGL + kq * 1024 + quad * 8;
    const float* aB1 = aB0 + (size_t)16 * DGL;

    f32x4 acc[2][8];
#pragma unroll
    for (int m = 0; m < 2; ++m)
#pragma unroll
        for (int nt = 0; nt < 8; ++nt) acc[m][nt] = (f32x4){0.f, 0.f, 0.f, 0.f};

    const char* wsB1b = (const char*)wsB1;

    // prologue: stage kci=0 into buf0 (wave fills its mh-half of its kq slice),
    // THEN issue A(0) loads (order matters: a0-wait transitively drains the stage DMA)
    {
        const char* gs = wsB1b + (size_t)(kq * 32 + 0) * 16384 + mh * 8192 + (size_t)l * 16;
        char* lp = smem + kq * 16384 + mh * 8192;
#pragma unroll
        for (int c = 0; c < 8; ++c) gload_lds16(gs + c * 1024, lp + c * 1024);
    }
    asm volatile("" ::: "memory");   // keep A-load issue AFTER stage issue
    float4 a0[4];
    a0[0] = *(const float4*)(aB0);
    a0[1] = *(const float4*)(aB0 + 4);
    a0[2] = *(const float4*)(aB1);
    a0[3] = *(const float4*)(aB1 + 4);

    int s = 0;
    for (int kci = 0; kci < 32; ++kci) {
        // split current A tile (compiler waits a0 -> stage(kci) retired, in-order vmcnt)
        short8 ahi[2], alo[2];
#pragma unroll
        for (int m = 0; m < 2; ++m) {
            float fa[8];
#pragma unroll
            for (int j = 0; j < 4; ++j) { fa[j] = a0[2 * m][j]; fa[j + 4] = a0[2 * m + 1][j]; }
            split8(fa, ahi[m], alo[m]);
        }

        // raw barrier: all waves' stage(kci) retired; all prev-iter reads of sb[s^1] done
        __builtin_amdgcn_sched_barrier(0);
        __builtin_amdgcn_s_barrier();

        // issue next stage + next A (latency hides under this tile's ds_read+MFMA)
        if (kci + 1 < 32) {
            const char* gs = wsB1b + (size_t)(kq * 32 + kci + 1) * 16384 + mh * 8192 + (size_t)l * 16;
            char* lp = smem + (s ^ 1) * 65536 + kq * 16384 + mh * 8192;
#pragma unroll
            for (int c = 0; c < 8; ++c) gload_lds16(gs + c * 1024, lp + c * 1024);
            asm volatile("" ::: "memory");
            a0[0] = *(const float4*)(aB0 + (kci + 1) * 32);
            a0[1] = *(const float4*)(aB0 + (kci + 1) * 32 + 4);
            a0[2] = *(const float4*)(aB1 + (kci + 1) * 32);
            a0[3] = *(const float4*)(aB1 + (kci + 1) * 32 + 4);
        }

        // compute from sb[s][kq]: frag f at byte (f*64 + l)*16
        const char* bp = smem + s * 65536 + kq * 16384 + (size_t)l * 16;
        short8 bh = *(const short8*)(bp + 0 * 1024);
        short8 bl = *(const short8*)(bp + 1 * 1024);
#pragma unroll
        for (int nt = 0; nt < 8; ++nt) {
            short8 bhn, bln;
            if (nt < 7) {
                bhn = *(const short8*)(bp + (2 * nt + 2) * 1024);
                bln = *(const short8*)(bp + (2 * nt + 3) * 1024);
            }
            acc[0][nt] = __builtin_amdgcn_mfma_f32_16x16x32_bf16(ahi[0], bh, acc[0][nt], 0, 0, 0);
            acc[0][nt] = __builtin_amdgcn_mfma_f32_16x16x32_bf16(ahi[0], bl, acc[0][nt], 0, 0, 0);
            acc[0][nt] = __builtin_amdgcn_mfma_f32_16x16x32_bf16(alo[0], bh, acc[0][nt], 0, 0, 0);
            acc[1][nt] = __builtin_amdgcn_mfma_f32_16x16x32_bf16(ahi[1], bh, acc[1][nt], 0, 0, 0);
            acc[1][nt] = __builtin_amdgcn_mfma_f32_16x16x32_bf16(ahi[1], bl, acc[1][nt], 0, 0, 0);
            acc[1][nt] = __builtin_amdgcn_mfma_f32_16x16x32_bf16(alo[1], bh, acc[1][nt], 0, 0, 0);
            bh = bhn; bl = bln;
        }
        s ^= 1;
    }
    __syncthreads();   // full drain; staging LDS is now dead -> alias epilogue arrays

    float* hsum = (float*)smem;                   // [64][132] = 33792 B
    float* ls   = (float*)(smem + 33792);         // [64][65]  = 16640 B
    float* wt   = (float*)(smem + 50432);         // [64][65]  = 16640 B

    // ---- reduce the 4 kq-partials per row-half (both mh halves in parallel) ----
    // C layout: row = mh*32 + m*16 + quad*4 + r, col = nt*16 + l15
    if (kq == 0) {
#pragma unroll
        for (int m = 0; m < 2; ++m)
#pragma unroll
            for (int nt = 0; nt < 8; ++nt)
#pragma unroll
                for (int r = 0; r < 4; ++r)
                    hsum[(mh * 32 + m * 16 + quad * 4 + r) * 132 + nt * 16 + l15] = acc[m][nt][r];
    }
    __syncthreads();
#pragma unroll
    for (int wv = 1; wv < 4; ++wv) {
        if (kq == wv) {
#pragma unroll
            for (int m = 0; m < 2; ++m)
#pragma unroll
                for (int nt = 0; nt < 8; ++nt)
#pragma unroll
                    for (int r = 0; r < 4; ++r)
                        hsum[(mh * 32 + m * 16 + quad * 4 + r) * 132 + nt * 16 + l15] += acc[m][nt][r];
        }
        __syncthreads();
    }

    // ---- epilogue: tail features + bias + silu, in place on hsum ----
    {
        const float sf = step_frac[0];
#pragma unroll
        for (int j = 0; j < 16; ++j) {
            const int idx = j * 512 + t;      // 0..8191 = 64 rows x 128 cols
            const int r = idx >> 7, c = idx & 127;
            float x = hsum[r * 132 + c];
            x += sf * W1[(size_t)4096 * HGL + c]
               + hn[row0 + r] * W1[(size_t)4097 * HGL + c]
               + cf[row0 + r] * W1[(size_t)4098 * HGL + c] + b1[c];
            hsum[r * 132 + c] = x / (1.0f + expf(-x));
        }
    }
    __syncthreads();

    // ---- GEMM2 via MFMA: wave w does 16 rows (mt2=w>>1) x 32 cols (nh2=w&1) ----
    const int mt2 = w >> 1, nh2 = w & 1;
    f32x4 acc2[2];
    acc2[0] = (f32x4){0.f, 0.f, 0.f, 0.f};
    acc2[1] = (f32x4){0.f, 0.f, 0.f, 0.f};
#pragma unroll
    for (int kc2 = 0; kc2 < 4; ++kc2) {
        const float4 va = *(const float4*)&hsum[(mt2 * 16 + l15) * 132 + kc2 * 32 + quad * 8];
        const float4 vb = *(const float4*)&hsum[(mt2 * 16 + l15) * 132 + kc2 * 32 + quad * 8 + 4];
        float fa[8];
#pragma unroll
        for (int j = 0; j < 4; ++j) { fa[j] = ((const float*)&va)[j]; fa[j + 4] = ((const float*)&vb)[j]; }
        short8 h2, lo2;
        split8(fa, h2, lo2);
#pragma unroll
        for (int ntp = 0; ntp < 2; ++ntp) {
            const int nt = nh2 * 2 + ntp;
            const short8 bh = *(const short8*)(wsB2 + ((kc2 * 4 + nt) * 2 + 0) * 512 + l * 8);
            const short8 bl = *(const short8*)(wsB2 + ((kc2 * 4 + nt) * 2 + 1) * 512 + l * 8);
            acc2[ntp] = __builtin_amdgcn_mfma_f32_16x16x32_bf16(h2,  bh, acc2[ntp], 0, 0, 0);
            acc2[ntp] = __builtin_amdgcn_mfma_f32_16x16x32_bf16(h2,  bl, acc2[ntp], 0, 0, 0);
            acc2[ntp] = __builtin_amdgcn_mfma_f32_16x16x32_bf16(lo2, bh, acc2[ntp], 0, 0, 0);
        }
    }

    // ---- logits out + ls stage, zero wt ----
#pragma unroll
    for (int ntp = 0; ntp < 2; ++ntp) {
        const int c = (nh2 * 2 + ntp) * 16 + l15;
        const float bv = b2v[c];
#pragma unroll
        for (int r = 0; r < 4; ++r) {
            const int lr = mt2 * 16 + quad * 4 + r;
            const float v = acc2[ntp][r] + bv;
            out_l[(size_t)(row0 + lr) * EGL + c] = v;
            ls[lr * 65 + c] = v;
        }
    }
    for (int i = t; i < 64 * 65; i += 512) wt[i] = 0.0f;
    __syncthreads();

    // ---- top-8 (+9th for gap), softmax, scatter, flag near-ties ----
    if (t < 64) {
        float vals[9]; int idxs[9];
#pragma unroll
        for (int i = 0; i < 9; ++i) { vals[i] = -INFINITY; idxs[i] = 0; }
        for (int e = 0; e < EGL; ++e) {
            const float v = ls[t * 65 + e];
            if (v > vals[8]) {
                int p = 8;
                while (p > 0 && v > vals[p - 1]) { vals[p] = vals[p - 1]; idxs[p] = idxs[p - 1]; --p; }
                vals[p] = v; idxs[p] = e;
            }
        }
        const float mx = vals[0];
        float wgt[8], ssum = 0.0f;
#pragma unroll
        for (int i = 0; i < 8; ++i) { wgt[i] = expf(vals[i] - mx); ssum += wgt[i]; }
        const float inv = 1.0f / ssum;
#pragma unroll
        for (int i = 0; i < 8; ++i) wt[t * 65 + idxs[i]] = wgt[i] * inv;
        if (vals[7] - vals[8] < DELTA) {
            int p = atomicAdd(gcount, 1);
            if (p < 16384) glist[p] = row0 + t;
        }
    }
    __syncthreads();

    for (int i = t; i < 64 * EGL; i += 512) {
        const int m = i >> 6, c = i & 63;
        out_w[(size_t)(row0 + m) * EGL + c] = wt[m * 65 + c];
    }
}

// ---- refine: fp32 recompute of listed rows ----
__global__ __launch_bounds__(512, 1) void refine_rows(
    const float* __restrict__ r_pooled, const float* __restrict__ step_frac,
    const float* __restrict__ hn, const float* __restrict__ cf,
    const float* __restrict__ W1, const float* __restrict__ b1,
    const float* __restrict__ W2, const float* __restrict__ b2,
    const int* __restrict__ gcount, const int* __restrict__ glist,
    float* __restrict__ out_w)
{
    __shared__ __align__(16) float als[DGL];
    __shared__ float part[4][128];
    __shared__ float hred[128];
    __shared__ float lb[64];
    __shared__ float wb[64];

    const int t = threadIdx.x;
    const int cnt = *gcount;
    const int c = t & 127, sl = t >> 7;

    for (int i = blockIdx.x; i < cnt; i += gridDim.x) {
        const int row = glist[i];
        __syncthreads();
        for (int j = t; j < DGL / 4; j += 512)
            *(float4*)&als[j * 4] = *(const float4*)&r_pooled[(size_t)row * DGL + j * 4];
        __syncthreads();

        float pr = 0.0f;
        const float* ap = als + sl * 1024;
        const float* wp = W1 + (size_t)(sl * 1024) * HGL + c;
#pragma unroll 8
        for (int k = 0; k < 1024; ++k) pr = fmaf(ap[k], wp[(size_t)k * HGL], pr);
        part[sl][c] = pr;
        __syncthreads();

        if (t < 128) {
            const float sf = step_frac[0];
            float x = part[0][t] + part[1][t] + part[2][t] + part[3][t];
            x += sf * W1[(size_t)4096 * HGL + t] + hn[row] * W1[(size_t)4097 * HGL + t]
               + cf[row] * W1[(size_t)4098 * HGL + t] + b1[t];
            hred[t] = x / (1.0f + expf(-x));
        }
        __syncthreads();
        if (t < 64) {
            float a = b2[t];
            for (int k = 0; k < HGL; ++k) a = fmaf(hred[k], W2[k * EGL + t], a);
            lb[t] = a; wb[t] = 0.0f;
        }
        __syncthreads();
        if (t == 0) {
            float vals[8]; int idxs[8];
#pragma unroll
            for (int q = 0; q < 8; ++q) { vals[q] = -INFINITY; idxs[q] = 0; }
            for (int e = 0; e < EGL; ++e) {
                const float v = lb[e];
                if (v > vals[7]) {
                    int p = 7;
                    while (p > 0 && v > vals[p - 1]) { vals[p] = vals[p - 1]; idxs[p] = idxs[p - 1]; --p; }
                    vals[p] = v; idxs[p] = e;
                }
            }
            const float mx = vals[0];
            float wgt[8], ssum = 0.0f;
#pragma unroll
            for (int q = 0; q < 8; ++q) { wgt[q] = expf(vals[q] - mx); ssum += wgt[q]; }
            const float inv = 1.0f / ssum;
#pragma unroll
            for (int q = 0; q < 8; ++q) wb[idxs[q]] = wgt[q] * inv;
        }
        __syncthreads();
        if (t < 64) out_w[(size_t)row * EGL + t] = wb[t];
    }
}

extern "C" void kernel_launch(void* const* d_in, const int* in_sizes, int n_in,
                              void* d_out, int out_size, void* d_ws, size_t ws_size,
                              hipStream_t stream) {
    const float* r_pooled    = (const float*)d_in[0];
    const float* step_frac   = (const float*)d_in[1];
    const float* hidden_norm = (const float*)d_in[2];
    const float* confidence  = (const float*)d_in[3];
    const float* W1          = (const float*)d_in[4];
    const float* b1          = (const float*)d_in[5];
    const float* W2          = (const float*)d_in[6];
    const float* b2          = (const float*)d_in[7];

    const int B = in_sizes[2];
    float* out_w = (float*)d_out;
    float* out_l = out_w + (size_t)B * EGL;

    unsigned short* wsB1 = (unsigned short*)d_ws;                    // 2 MB
    unsigned short* wsB2 = (unsigned short*)((char*)d_ws + 2097152); // 32 KB
    int* gcount = (int*)((char*)d_ws + 2129920);
    int* glist  = (int*)((char*)d_ws + 2129984);                     // 64 KB

    hipLaunchKernelGGL(pack_w1, dim3(1024), dim3(64), 0, stream, W1, wsB1);
    hipLaunchKernelGGL(pack_w2, dim3(16), dim3(64), 0, stream, W2, wsB2, gcount);
    hipLaunchKernelGGL(router_main, dim3(B / 64), dim3(512), 0, stream,
                       r_pooled, step_frac, hidden_norm, confidence,
                       W1, b1, b2, wsB1, wsB2, gcount, glist, out_w, out_l);
    hipLaunchKernelGGL(refine_rows, dim3(256), dim3(512), 0, stream,
                       r_pooled, step_frac, hidden_norm, confidence,
                       W1, b1, W2, b2, gcount, glist, out_w);
}